// Round 8
// baseline (185.165 us; speedup 1.0000x reference)
//
#include <hip/hip_runtime.h>
#include <cmath>

#define QN    65536
#define KVN   65536
#define CD    256
#define NH    8
#define NE    524288
#define SCL   0.0625f      // 1/sqrt(256)
#define LNEPS 1e-5f
#define LOG2E 1.4426950408889634f

typedef __bf16 bf16x8 __attribute__((ext_vector_type(8)));
typedef float  f32x4  __attribute__((ext_vector_type(4)));
typedef float  f32x2  __attribute__((ext_vector_type(2)));

__device__ __forceinline__ float b2f(ushort u) {
    return __builtin_bit_cast(float, (unsigned)u << 16);
}
__device__ __forceinline__ float blo(unsigned u) {
    return __builtin_bit_cast(float, u << 16);
}
__device__ __forceinline__ float bhi(unsigned u) {
    return __builtin_bit_cast(float, u & 0xFFFF0000u);
}
__device__ __forceinline__ ushort f2bf(float f) {
    unsigned u = __builtin_bit_cast(unsigned, f);
    return (ushort)((u + 0x7FFFu + ((u >> 16) & 1u)) >> 16);   // RNE
}

#if __has_builtin(__builtin_amdgcn_exp2f)
__device__ __forceinline__ float fexp2(float x) { return __builtin_amdgcn_exp2f(x); }
#else
__device__ __forceinline__ float fexp2(float x) {
    float r; asm volatile("v_exp_f32 %0, %1" : "=v"(r) : "v"(x)); return r;
}
#endif

// ---- fp8 e4m3 pack/unpack (HW converts on gfx950; SW fallback kept for safety).
// Pipeline only needs encode/decode SELF-CONSISTENCY, so OCP-vs-fnuz is moot.
#if __has_builtin(__builtin_amdgcn_cvt_pk_fp8_f32) && __has_builtin(__builtin_amdgcn_cvt_pk_f32_fp8)
#define HW_FP8 1
#endif

__device__ __forceinline__ unsigned enc1_fp8(float f) {   // SW fallback (FTZ, RNE)
    unsigned s = f < 0.f ? 0x80u : 0u;
    float a = fabsf(f);
    if (!(a >= 0.015625f)) return s;
    a = fminf(a, 448.f);
    unsigned ua = __builtin_bit_cast(unsigned, a);
    ua += 0x7FFFFu + ((ua >> 20) & 1u);
    if ((ua >> 23) > 135u) return s | 0x7Eu;
    return s | (((ua >> 23) - 120u) << 3) | ((ua >> 20) & 7u);
}
__device__ __forceinline__ float dec1_fp8(unsigned b) {   // SW fallback
    unsigned s = (b & 0x80u) << 24;
    unsigned e = (b >> 3) & 15u, m = b & 7u;
    if (e == 0u) {
        float v = (float)m * 0.001953125f;
        return __builtin_bit_cast(float, s | __builtin_bit_cast(unsigned, v));
    }
    return __builtin_bit_cast(float, s | ((e + 120u) << 23) | (m << 20));
}
__device__ __forceinline__ unsigned pk_fp8x4(float a, float b, float c, float d) {
#ifdef HW_FP8
    int v = __builtin_amdgcn_cvt_pk_fp8_f32(a, b, 0, false);
    v     = __builtin_amdgcn_cvt_pk_fp8_f32(c, d, v, true);
    return (unsigned)v;
#else
    return enc1_fp8(a) | (enc1_fp8(b) << 8) | (enc1_fp8(c) << 16) | (enc1_fp8(d) << 24);
#endif
}
__device__ __forceinline__ void un_fp8x4(unsigned u, float o[4]) {
#ifdef HW_FP8
    f32x2 lo = __builtin_amdgcn_cvt_pk_f32_fp8((int)u, false);
    f32x2 hi = __builtin_amdgcn_cvt_pk_f32_fp8((int)u, true);
    o[0] = lo[0]; o[1] = lo[1]; o[2] = hi[0]; o[3] = hi[1];
#else
    o[0] = dec1_fp8(u & 255u); o[1] = dec1_fp8((u >> 8) & 255u);
    o[2] = dec1_fp8((u >> 16) & 255u); o[3] = dec1_fp8(u >> 24);
#endif
}

#define GLD16(g, l) __builtin_amdgcn_global_load_lds( \
    (const __attribute__((address_space(1))) unsigned int*)(const void*)(g), \
    (__attribute__((address_space(3))) unsigned int*)(void*)(l), 16, 0, 0)

// ---------------------------------------------------------------- fused prep:
// blk [0, LNB):          LN(q) -> bf16 qn           (4 rows/block)
// blk [LNB, LNB+192):    wq|wk|wo fp32 -> bf16      (1024 els/block)
// blk [.., +NE/256):     CSR row_lo fill
// blk [.., +LNB):        k fp32 -> bf16 kb          (4 rows/block)
#define LNB   (QN / 4)
#define RLB   (NE / 256)
__global__ __launch_bounds__(256) void prep_k(const float* __restrict__ q,
                                              const float* __restrict__ k,
                                              const float* __restrict__ lnw,
                                              const float* __restrict__ lnb,
                                              const float* __restrict__ wq,
                                              const float* __restrict__ wk,
                                              const float* __restrict__ wo,
                                              const int* __restrict__ dst,
                                              ushort* __restrict__ qn,
                                              ushort* __restrict__ kb,
                                              ushort* __restrict__ wb,
                                              int* __restrict__ row_lo) {
    const int blk = blockIdx.x;
    if (blk < LNB) {
        int row  = (blk << 2) + (threadIdx.x >> 6);
        int lane = threadIdx.x & 63;
        float4 v = *(const float4*)(q + (size_t)row * CD + (lane << 2));
        float s  = v.x + v.y + v.z + v.w;
        float s2 = v.x * v.x + v.y * v.y + v.z * v.z + v.w * v.w;
        #pragma unroll
        for (int m = 1; m < 64; m <<= 1) {
            s  += __shfl_xor(s, m);
            s2 += __shfl_xor(s2, m);
        }
        float mu   = s * (1.0f / CD);
        float rstd = rsqrtf(s2 * (1.0f / CD) - mu * mu + LNEPS);
        float4 w = *(const float4*)(lnw + (lane << 2));
        float4 b = *(const float4*)(lnb + (lane << 2));
        ushort4 o;
        o.x = f2bf((v.x - mu) * rstd * w.x + b.x);
        o.y = f2bf((v.y - mu) * rstd * w.y + b.y);
        o.z = f2bf((v.z - mu) * rstd * w.z + b.z);
        o.w = f2bf((v.w - mu) * rstd * w.w + b.w);
        *(ushort4*)(qn + (size_t)row * CD + (lane << 2)) = o;
    } else if (blk < LNB + 192) {
        int idx4 = ((blk - LNB) * 256 + threadIdx.x) * 4;   // 0 .. 3*65536
        int mat  = idx4 >> 16;
        int off  = idx4 & 65535;
        const float* src = (mat == 0) ? wq : (mat == 1) ? wk : wo;
        float4 v = *(const float4*)(src + off);
        ushort4 o;
        o.x = f2bf(v.x); o.y = f2bf(v.y); o.z = f2bf(v.z); o.w = f2bf(v.w);
        *(ushort4*)(wb + idx4) = o;
    } else if (blk < LNB + 192 + RLB) {
        int e = (blk - LNB - 192) * 256 + threadIdx.x;
        int d     = dst[e];
        int dprev = (e == 0) ? -1 : dst[e - 1];
        for (int qq = dprev + 1; qq <= d; ++qq) row_lo[qq] = e;
        if (e == NE - 1)
            for (int qq = d + 1; qq <= QN; ++qq) row_lo[qq] = NE;
    } else {
        int row  = ((blk - LNB - 192 - RLB) << 2) + (threadIdx.x >> 6);
        int lane = threadIdx.x & 63;
        float4 v = *(const float4*)(k + (size_t)row * CD + (lane << 2));
        ushort4 o;
        o.x = f2bf(v.x); o.y = f2bf(v.y); o.z = f2bf(v.z); o.w = f2bf(v.w);
        *(ushort4*)(kb + (size_t)row * CD + (lane << 2)) = o;
    }
}

// ---------------------------------------------------------------- persistent bf16 GEMM
// Proven R2 structure. One block per CU (LDS 128 KB), 512 threads = 8 waves
// (2m x 4n), tile 128x128. B panel in LDS once; A via 8-slot GLD16 ring,
// stage-ahead-6, counted vmcnt; one barrier per K-step; swapped-operand MFMA.
// EPI 0: z0 -> bf16 out (qp); z1 -> fp8 e4m3 out (kp, halves edge-gather bytes).
// EPI 1: f32 out + resid.
template<int EPI, int NT>
__global__ __launch_bounds__(512) void gemm2_k(const ushort* __restrict__ A0,
                                               const ushort* __restrict__ A1,
                                               const ushort* __restrict__ B0,
                                               const ushort* __restrict__ B1,
                                               const float* __restrict__ bias0,
                                               const float* __restrict__ bias1,
                                               const float* __restrict__ resid,
                                               void* __restrict__ C0,
                                               void* __restrict__ C1) {
    const bool second = (blockIdx.z != 0);
    const ushort* Ap   = second ? A1 : A0;
    const ushort* B    = second ? B1 : B0;
    const float*  bias = second ? bias1 : bias0;
    void*         Cout = second ? C1 : C0;

    __shared__ __align__(16) ushort Bs[8][4096];   // 64 KB: full B panel, 8 k-slices
    __shared__ __align__(16) ushort As[8][4096];   // 64 KB: A ring, 8 slots

    const int t    = threadIdx.x;
    const int lane = t & 63;
    const int wid  = t >> 6;             // 0..7
    const int wm   = wid & 1;            // 2 wave-rows
    const int wn   = wid >> 1;           // 4 wave-cols
    const size_t bn  = (size_t)blockIdx.y * 128;
    size_t bm = (size_t)blockIdx.x * (NT * 128);

    const int sr = t >> 2;               // 0..127 staging row
    const int sc = (t & 3) * 8;          // staging col (8 elems = 16B)

    constexpr int E = (EPI == 0) ? 8 : 16;   // epilogue vmem instrs

    f32x4 acc[4][2] = {};
    f32x4 biasv[2];
    #pragma unroll
    for (int ni = 0; ni < 2; ++ni)
        biasv[ni] = *(const f32x4*)(bias + bn + wn * 32 + ni * 16 + ((lane >> 4) << 2));

    // ---- prologue: whole B panel + A slots 0..5
    #pragma unroll
    for (int s = 0; s < 8; ++s)
        GLD16(B + (bn + sr) * CD + (s << 5) + sc, &Bs[s][wid << 9]);
    #pragma unroll
    for (int s = 0; s < 6; ++s)
        GLD16(Ap + (bm + sr) * CD + (s << 5) + sc, &As[s][wid << 9]);
    asm volatile("" : "+v"(biasv[0]), "+v"(biasv[1]));

#define KSTEP(KT, VM, GUARD)                                                          \
  {                                                                                   \
    if (GUARD) {                                                                      \
      const ushort* ga_ = Ap + (bm + (((KT) >= 2) ? 128 : 0) + sr) * CD               \
                          + ((((KT) + 6) & 7) << 5) + sc;                             \
      GLD16(ga_, &As[((KT) + 6) & 7][wid << 9]);                                      \
    }                                                                                 \
    asm volatile("s_waitcnt vmcnt(%0) lgkmcnt(0)\n\ts_barrier" :: "i"(VM) : "memory");\
    {                                                                                 \
      const int kq_ = (lane >> 4) << 3;                                               \
      bf16x8 af_[4], bg_[2];                                                          \
      _Pragma("unroll")                                                               \
      for (int mi = 0; mi < 4; ++mi)                                                  \
        af_[mi] = *(const bf16x8*)&As[(KT) & 7][((wm * 64 + mi * 16 + (lane & 15)) << 5) + kq_]; \
      _Pragma("unroll")                                                               \
      for (int ni = 0; ni < 2; ++ni)                                                  \
        bg_[ni] = *(const bf16x8*)&Bs[(KT)][((wn * 32 + ni * 16 + (lane & 15)) << 5) + kq_];     \
      _Pragma("unroll")                                                               \
      for (int mi = 0; mi < 4; ++mi)                                                  \
        _Pragma("unroll")                                                             \
        for (int ni = 0; ni < 2; ++ni)                                                \
          acc[mi][ni] = __builtin_amdgcn_mfma_f32_16x16x32_bf16(bg_[ni], af_[mi], acc[mi][ni], 0, 0, 0); \
    }                                                                                 \
  }

#define EPILOG()                                                                      \
  {                                                                                   \
    _Pragma("unroll")                                                                 \
    for (int mi = 0; mi < 4; ++mi) {                                                  \
      const size_t row_ = bm + wm * 64 + mi * 16 + (lane & 15);                       \
      _Pragma("unroll")                                                               \
      for (int ni = 0; ni < 2; ++ni) {                                                \
        const size_t col_ = bn + wn * 32 + ni * 16 + ((lane >> 4) << 2);              \
        if (EPI == 0) {                                                               \
          if (second) {          /* kp: fp8 e4m3, 4 cols -> 4 bytes */                \
            unsigned o8_ = pk_fp8x4(acc[mi][ni][0] + biasv[ni][0],                    \
                                    acc[mi][ni][1] + biasv[ni][1],                    \
                                    acc[mi][ni][2] + biasv[ni][2],                    \
                                    acc[mi][ni][3] + biasv[ni][3]);                   \
            *(unsigned*)((unsigned char*)Cout + row_ * CD + col_) = o8_;              \
          } else {                                                                    \
            ushort4 o_;                                                               \
            o_.x = f2bf(acc[mi][ni][0] + biasv[ni][0]);                               \
            o_.y = f2bf(acc[mi][ni][1] + biasv[ni][1]);                               \
            o_.z = f2bf(acc[mi][ni][2] + biasv[ni][2]);                               \
            o_.w = f2bf(acc[mi][ni][3] + biasv[ni][3]);                               \
            *(ushort4*)((ushort*)Cout + row_ * CD + col_) = o_;                       \
          }                                                                           \
        } else {                                                                      \
          f32x4 rs_ = *(const f32x4*)(resid + row_ * CD + col_);                      \
          f32x4 o_;                                                                   \
          o_[0] = acc[mi][ni][0] + biasv[ni][0] + rs_[0];                             \
          o_[1] = acc[mi][ni][1] + biasv[ni][1] + rs_[1];                             \
          o_[2] = acc[mi][ni][2] + biasv[ni][2] + rs_[2];                             \
          o_[3] = acc[mi][ni][3] + biasv[ni][3] + rs_[3];                             \
          *(f32x4*)((float*)Cout + row_ * CD + col_) = o_;                            \
        }                                                                             \
        acc[mi][ni] = (f32x4){0.f, 0.f, 0.f, 0.f};                                    \
      }                                                                               \
    }                                                                                 \
    asm volatile("" ::: "memory");                                                    \
  }

    // ---- tile 0
    KSTEP(0, 6, 1) KSTEP(1, 6, 1) KSTEP(2, 6, 1) KSTEP(3, 6, 1)
    KSTEP(4, 6, 1) KSTEP(5, 6, 1) KSTEP(6, 6, 1) KSTEP(7, 6, 1)
    EPILOG();
    bm += 128;

    // ---- middle tiles
    for (int tt = 1; tt < NT - 1; ++tt) {
        KSTEP(0, 6 + E, 1) KSTEP(1, 6 + E, 1) KSTEP(2, 6 + E, 1) KSTEP(3, 6 + E, 1)
        KSTEP(4, 6 + E, 1) KSTEP(5, 6 + E, 1) KSTEP(6, 6, 1)     KSTEP(7, 6, 1)
        EPILOG();
        bm += 128;
    }

    // ---- last tile
    KSTEP(0, 6 + E, 1) KSTEP(1, 6 + E, 1) KSTEP(2, 5 + E, 0) KSTEP(3, 4 + E, 0)
    KSTEP(4, 3 + E, 0) KSTEP(5, 2 + E, 0) KSTEP(6, 1, 0)     KSTEP(7, 0, 0)
    EPILOG();

#undef KSTEP
#undef EPILOG
}

// ---------------------------------------------------------------- edge attention
// v7 = v6 structure (proven correct) with kp in fp8 e4m3: per edge each lane
// gathers 4 B (was 8 B) of its own 4 output channels and decodes with 2
// cvt_pk_f32_fp8.  R7 evidence: 2.8-3.0 TB/s regardless of occupancy (38-63%)
// and instruction count (4x range) => random-gather BW ceiling; bytes are the
// only lever.  Everything else byte-identical to v6.
__global__ __launch_bounds__(64) void edge_attn_k(const ushort* __restrict__ qp,
                                                  const unsigned char* __restrict__ kp8,
                                                  const float* __restrict__ bias,
                                                  const int* __restrict__ src,
                                                  const int* __restrict__ row_lo,
                                                  ushort* __restrict__ ao,
                                                  float* __restrict__ simw) {
    const int q    = blockIdx.x;
    const int lane = threadIdx.x;
    const int e    = lane >> 3;          // output-channel-block slot 0..7
    const int h    = lane & 7;           // head
    const int lo = row_lo[q];
    const int hi = row_lo[q + 1];
    const int deg = hi - lo;
    const float SC2 = SCL * LOG2E;

    // own q channels h*32+e*4 .. +3 (2 uints = 4 bf16)
    const uint2 qv2 = *(const uint2*)(qp + (size_t)q * CD + (h << 5) + (e << 2));

    f32x4 acc = {0.f, 0.f, 0.f, 0.f};    // final channels h*32 + e*4 .. +3
    float m = -INFINITY, s = 0.f;
    float wval0 = -INFINITY, wval1 = -INFINITY;

    for (int base = lo; base < hi; base += 8) {
        // src for edges base..base+7 (lanes 0-7, guarded), bias own (coalesced)
        int sv = 0;
        if (lane < 8 && base + lane < hi) sv = src[base + lane];
        float bv = 0.f;
        if (lane < (hi - base) * 8) bv = bias[(size_t)base * NH + lane] * SC2;

        // per-edge 4-B fp8 slice of own channels (wave-uniform guard per edge)
        unsigned ku[8];
        #pragma unroll
        for (int ep = 0; ep < 8; ++ep) {
            ku[ep] = 0u;
            if (base + ep < hi) {
                int sidx = __shfl(sv, ep);
                ku[ep] = *(const unsigned*)(kp8 + (size_t)sidx * CD + (h << 5) + (e << 2));
            }
        }
        // partial dots over own 4 channels (fp8 decode: 2 cvt_pk per edge)
        float p[8];
        #pragma unroll
        for (int ep = 0; ep < 8; ++ep) {
            float kv[4];
            un_fp8x4(ku[ep], kv);
            float d;
            d = blo(qv2.x) * kv[0];
            d = fmaf(bhi(qv2.x), kv[1], d);
            d = fmaf(blo(qv2.y), kv[2], d);
            d = fmaf(bhi(qv2.y), kv[3], d);
            p[ep] = d;
        }
        // butterfly over e-lanes (h preserved): all lanes get full 32-ch dots
        #pragma unroll
        for (int r = 8; r <= 32; r <<= 1) {
            #pragma unroll
            for (int ep = 0; ep < 8; ++ep)
                p[ep] += __shfl_xor(p[ep], r);
        }
        // + bias (bpermute from the coalesced bv); inactive -> -inf
        float sims[8];
        #pragma unroll
        for (int ep = 0; ep < 8; ++ep) {
            float bvp = __shfl(bv, (ep << 3) + h);
            sims[ep] = (base + ep < hi) ? fmaf(p[ep], SC2, bvp) : -INFINITY;
        }
        // local per-head softmax (identical across the 8 e-lanes of a head)
        float cmax = sims[0];
        #pragma unroll
        for (int ep = 1; ep < 8; ++ep) cmax = fmaxf(cmax, sims[ep]);
        const float mnew  = fmaxf(m, cmax);
        const float scale = fexp2(m - mnew);     // first chunk: exp2(-inf)=0
        acc[0] *= scale; acc[1] *= scale; acc[2] *= scale; acc[3] *= scale;
        float esum = 0.f;
        #pragma unroll
        for (int ep = 0; ep < 8; ++ep) {
            const float ex = fexp2(sims[ep] - mnew);   // inactive: 0
            float kv[4];
            un_fp8x4(ku[ep], kv);
            esum += ex;
            acc[0] = fmaf(ex, kv[0], acc[0]);
            acc[1] = fmaf(ex, kv[1], acc[1]);
            acc[2] = fmaf(ex, kv[2], acc[2]);
            acc[3] = fmaf(ex, kv[3], acc[3]);
        }
        s = s * scale + esum;
        m = mnew;

        // own-edge sim (edge base+e, head h) via cndmask tree
        float ta = (e & 1) ? sims[1] : sims[0];
        float tb = (e & 1) ? sims[3] : sims[2];
        float tc = (e & 1) ? sims[5] : sims[4];
        float td = (e & 1) ? sims[7] : sims[6];
        float te = (e & 2) ? tb : ta;
        float tf = (e & 2) ? td : tc;
        float own = (e & 4) ? tf : te;
        if (deg <= 16) {
            if (base == lo) wval0 = own; else wval1 = own;
        } else if (base + e < hi) {
            simw[(size_t)base * NH + lane] = own;   // raw log2 sims staged
        }
    }

    // s, m are full per-head values (identical across e-lanes of the head)
    const float inv = 1.0f / (s + 1e-8f);

    ushort4 o;
    o.x = f2bf(acc[0] * inv);
    o.y = f2bf(acc[1] * inv);
    o.z = f2bf(acc[2] * inv);
    o.w = f2bf(acc[3] * inv);
    *(ushort4*)(ao + (size_t)q * CD + (h << 5) + (e << 2)) = o;

    if (deg > 0) {
        if (deg <= 8) {
            if (lane < (deg << 3))
                simw[(size_t)lo * NH + lane] = fexp2(wval0 - m) * inv;
        } else if (deg <= 16) {
            simw[(size_t)lo * NH + lane] = fexp2(wval0 - m) * inv;
            if (lane < ((deg - 8) << 3))
                simw[(size_t)(lo + 8) * NH + lane] = fexp2(wval1 - m) * inv;
        } else {
            asm volatile("s_waitcnt vmcnt(0)" ::: "memory");   // drain sim stores
            for (int i = lane; i < deg * 8; i += 64) {
                size_t idx = (size_t)lo * NH + i;   // head = i&7 = lane&7 = h
                float v = simw[idx];
                simw[idx] = fexp2(v - m) * inv;
            }
        }
    }
}

// ---------------------------------------------------------------- launch
extern "C" void kernel_launch(void* const* d_in, const int* in_sizes, int n_in,
                              void* d_out, int out_size, void* d_ws, size_t ws_size,
                              hipStream_t stream) {
    const float* q    = (const float*)d_in[0];
    const float* k    = (const float*)d_in[1];
    const float* bias = (const float*)d_in[2];
    const float* lnw  = (const float*)d_in[3];
    const float* lnb  = (const float*)d_in[4];
    const float* wq   = (const float*)d_in[5];
    const float* bq   = (const float*)d_in[6];
    const float* wk   = (const float*)d_in[7];
    const float* bk   = (const float*)d_in[8];
    const float* wo   = (const float*)d_in[9];
    const float* bo   = (const float*)d_in[10];
    const int*   src  = (const int*)d_in[11];
    const int*   dst  = (const int*)d_in[12];

    float* out_m = (float*)d_out;                   // [QN][CD] fp32
    float* out_w = out_m + (size_t)QN * CD;         // [NE][NH] fp32 (weights)

    ushort* qn_b = (ushort*)d_ws;                   // [QN][CD]  LN(q) bf16 -> reused as attn_out
    ushort* qp_b = qn_b + (size_t)QN * CD;          // [QN][CD]  qp bf16
    ushort* kp_b = qp_b + (size_t)QN * CD;          // [KVN][CD] kp region (fp8 uses half)
    ushort* wb   = kp_b + (size_t)KVN * CD;         // 3 x [256*256] bf16 weights
    int*    rowlo = (int*)(wb + 3 * 65536);         // [QN+1]

    unsigned char* kp8 = (unsigned char*)kp_b;      // [KVN][CD] fp8 e4m3

    // kb (k converted to bf16) lives in the out_m region: consumed by gemm2<0>,
    // and out_m is only written by the final gemm2<1>.
    ushort* kb = (ushort*)d_out;                    // [KVN][CD] bf16 (32 MB of 64)

    prep_k<<<dim3(LNB + 192 + RLB + LNB), dim3(256), 0, stream>>>(
        q, k, lnw, lnb, wq, wk, wo, dst, qn_b, kb, wb, rowlo);

    // z=0: qp = LN(q)@wq -> bf16 ; z=1: kp = kb@wk -> fp8 e4m3
    gemm2_k<0, 8><<<dim3(64, 2, 2), dim3(512), 0, stream>>>(
        qn_b, kb, wb, wb + 65536, bq, bk, nullptr, qp_b, kp8);

    edge_attn_k<<<dim3(QN), dim3(64), 0, stream>>>(
        qp_b, kp8, bias, src, rowlo, qn_b /*ao*/, out_w);

    // out = attn_out@wo + bo + q
    gemm2_k<1, 4><<<dim3(128, 2, 1), dim3(512), 0, stream>>>(
        qn_b, qn_b, wb + 131072, wb + 131072, bo, bo, q, out_m, out_m);
}

// Round 9
// 182.147 us; speedup vs baseline: 1.0166x; 1.0166x over previous
//
#include <hip/hip_runtime.h>
#include <cmath>

#define QN    65536
#define KVN   65536
#define CD    256
#define NH    8
#define NE    524288
#define SCL   0.0625f      // 1/sqrt(256)
#define LNEPS 1e-5f
#define LOG2E 1.4426950408889634f

typedef __bf16 bf16x8 __attribute__((ext_vector_type(8)));
typedef float  f32x4  __attribute__((ext_vector_type(4)));

__device__ __forceinline__ float b2f(ushort u) {
    return __builtin_bit_cast(float, (unsigned)u << 16);
}
__device__ __forceinline__ float blo(unsigned u) {
    return __builtin_bit_cast(float, u << 16);
}
__device__ __forceinline__ float bhi(unsigned u) {
    return __builtin_bit_cast(float, u & 0xFFFF0000u);
}
__device__ __forceinline__ ushort f2bf(float f) {
    unsigned u = __builtin_bit_cast(unsigned, f);
    return (ushort)((u + 0x7FFFu + ((u >> 16) & 1u)) >> 16);   // RNE
}

#if __has_builtin(__builtin_amdgcn_exp2f)
__device__ __forceinline__ float fexp2(float x) { return __builtin_amdgcn_exp2f(x); }
#else
__device__ __forceinline__ float fexp2(float x) {
    float r; asm volatile("v_exp_f32 %0, %1" : "=v"(r) : "v"(x)); return r;
}
#endif

#define GLD16(g, l) __builtin_amdgcn_global_load_lds( \
    (const __attribute__((address_space(1))) unsigned int*)(const void*)(g), \
    (__attribute__((address_space(3))) unsigned int*)(void*)(l), 16, 0, 0)

// ---------------------------------------------------------------- fused prep:
// blk [0, LNB):          LN(q) -> bf16 qn           (4 rows/block)
// blk [LNB, LNB+192):    wq|wk|wo fp32 -> bf16      (1024 els/block)
// blk [.., +NE/256):     CSR row_lo fill
// blk [.., +LNB):        k fp32 -> bf16 kb          (4 rows/block)
#define LNB   (QN / 4)
#define RLB   (NE / 256)
__global__ __launch_bounds__(256) void prep_k(const float* __restrict__ q,
                                              const float* __restrict__ k,
                                              const float* __restrict__ lnw,
                                              const float* __restrict__ lnb,
                                              const float* __restrict__ wq,
                                              const float* __restrict__ wk,
                                              const float* __restrict__ wo,
                                              const int* __restrict__ dst,
                                              ushort* __restrict__ qn,
                                              ushort* __restrict__ kb,
                                              ushort* __restrict__ wb,
                                              int* __restrict__ row_lo) {
    const int blk = blockIdx.x;
    if (blk < LNB) {
        int row  = (blk << 2) + (threadIdx.x >> 6);
        int lane = threadIdx.x & 63;
        float4 v = *(const float4*)(q + (size_t)row * CD + (lane << 2));
        float s  = v.x + v.y + v.z + v.w;
        float s2 = v.x * v.x + v.y * v.y + v.z * v.z + v.w * v.w;
        #pragma unroll
        for (int m = 1; m < 64; m <<= 1) {
            s  += __shfl_xor(s, m);
            s2 += __shfl_xor(s2, m);
        }
        float mu   = s * (1.0f / CD);
        float rstd = rsqrtf(s2 * (1.0f / CD) - mu * mu + LNEPS);
        float4 w = *(const float4*)(lnw + (lane << 2));
        float4 b = *(const float4*)(lnb + (lane << 2));
        ushort4 o;
        o.x = f2bf((v.x - mu) * rstd * w.x + b.x);
        o.y = f2bf((v.y - mu) * rstd * w.y + b.y);
        o.z = f2bf((v.z - mu) * rstd * w.z + b.z);
        o.w = f2bf((v.w - mu) * rstd * w.w + b.w);
        *(ushort4*)(qn + (size_t)row * CD + (lane << 2)) = o;
    } else if (blk < LNB + 192) {
        int idx4 = ((blk - LNB) * 256 + threadIdx.x) * 4;   // 0 .. 3*65536
        int mat  = idx4 >> 16;
        int off  = idx4 & 65535;
        const float* src = (mat == 0) ? wq : (mat == 1) ? wk : wo;
        float4 v = *(const float4*)(src + off);
        ushort4 o;
        o.x = f2bf(v.x); o.y = f2bf(v.y); o.z = f2bf(v.z); o.w = f2bf(v.w);
        *(ushort4*)(wb + idx4) = o;
    } else if (blk < LNB + 192 + RLB) {
        int e = (blk - LNB - 192) * 256 + threadIdx.x;
        int d     = dst[e];
        int dprev = (e == 0) ? -1 : dst[e - 1];
        for (int qq = dprev + 1; qq <= d; ++qq) row_lo[qq] = e;
        if (e == NE - 1)
            for (int qq = d + 1; qq <= QN; ++qq) row_lo[qq] = NE;
    } else {
        int row  = ((blk - LNB - 192 - RLB) << 2) + (threadIdx.x >> 6);
        int lane = threadIdx.x & 63;
        float4 v = *(const float4*)(k + (size_t)row * CD + (lane << 2));
        ushort4 o;
        o.x = f2bf(v.x); o.y = f2bf(v.y); o.z = f2bf(v.z); o.w = f2bf(v.w);
        *(ushort4*)(kb + (size_t)row * CD + (lane << 2)) = o;
    }
}

// ---------------------------------------------------------------- persistent bf16 GEMM
// Proven R2 kernel, byte-identical. One block per CU (LDS 128 KB), 512 threads
// = 8 waves (2m x 4n), tile 128x128. B panel in LDS once; A via 8-slot GLD16
// ring, stage-ahead-6, counted vmcnt; one barrier per K-step; swapped-operand
// MFMA -> vectorized epilogue. EPI 0: bf16 out (E=8). EPI 1: f32 + resid (E=16).
template<int EPI, int NT>
__global__ __launch_bounds__(512) void gemm2_k(const ushort* __restrict__ A0,
                                               const ushort* __restrict__ A1,
                                               const ushort* __restrict__ B0,
                                               const ushort* __restrict__ B1,
                                               const float* __restrict__ bias0,
                                               const float* __restrict__ bias1,
                                               const float* __restrict__ resid,
                                               void* __restrict__ C0,
                                               void* __restrict__ C1) {
    const bool second = (blockIdx.z != 0);
    const ushort* Ap   = second ? A1 : A0;
    const ushort* B    = second ? B1 : B0;
    const float*  bias = second ? bias1 : bias0;
    void*         Cout = second ? C1 : C0;

    __shared__ __align__(16) ushort Bs[8][4096];   // 64 KB: full B panel, 8 k-slices
    __shared__ __align__(16) ushort As[8][4096];   // 64 KB: A ring, 8 slots

    const int t    = threadIdx.x;
    const int lane = t & 63;
    const int wid  = t >> 6;             // 0..7
    const int wm   = wid & 1;            // 2 wave-rows
    const int wn   = wid >> 1;           // 4 wave-cols
    const size_t bn  = (size_t)blockIdx.y * 128;
    size_t bm = (size_t)blockIdx.x * (NT * 128);

    const int sr = t >> 2;               // 0..127 staging row
    const int sc = (t & 3) * 8;          // staging col (8 elems = 16B)

    constexpr int E = (EPI == 0) ? 8 : 16;   // epilogue vmem instrs

    f32x4 acc[4][2] = {};
    f32x4 biasv[2];
    #pragma unroll
    for (int ni = 0; ni < 2; ++ni)
        biasv[ni] = *(const f32x4*)(bias + bn + wn * 32 + ni * 16 + ((lane >> 4) << 2));

    // ---- prologue: whole B panel + A slots 0..5
    #pragma unroll
    for (int s = 0; s < 8; ++s)
        GLD16(B + (bn + sr) * CD + (s << 5) + sc, &Bs[s][wid << 9]);
    #pragma unroll
    for (int s = 0; s < 6; ++s)
        GLD16(Ap + (bm + sr) * CD + (s << 5) + sc, &As[s][wid << 9]);
    asm volatile("" : "+v"(biasv[0]), "+v"(biasv[1]));

#define KSTEP(KT, VM, GUARD)                                                          \
  {                                                                                   \
    if (GUARD) {                                                                      \
      const ushort* ga_ = Ap + (bm + (((KT) >= 2) ? 128 : 0) + sr) * CD               \
                          + ((((KT) + 6) & 7) << 5) + sc;                             \
      GLD16(ga_, &As[((KT) + 6) & 7][wid << 9]);                                      \
    }                                                                                 \
    asm volatile("s_waitcnt vmcnt(%0) lgkmcnt(0)\n\ts_barrier" :: "i"(VM) : "memory");\
    {                                                                                 \
      const int kq_ = (lane >> 4) << 3;                                               \
      bf16x8 af_[4], bg_[2];                                                          \
      _Pragma("unroll")                                                               \
      for (int mi = 0; mi < 4; ++mi)                                                  \
        af_[mi] = *(const bf16x8*)&As[(KT) & 7][((wm * 64 + mi * 16 + (lane & 15)) << 5) + kq_]; \
      _Pragma("unroll")                                                               \
      for (int ni = 0; ni < 2; ++ni)                                                  \
        bg_[ni] = *(const bf16x8*)&Bs[(KT)][((wn * 32 + ni * 16 + (lane & 15)) << 5) + kq_];     \
      _Pragma("unroll")                                                               \
      for (int mi = 0; mi < 4; ++mi)                                                  \
        _Pragma("unroll")                                                             \
        for (int ni = 0; ni < 2; ++ni)                                                \
          acc[mi][ni] = __builtin_amdgcn_mfma_f32_16x16x32_bf16(bg_[ni], af_[mi], acc[mi][ni], 0, 0, 0); \
    }                                                                                 \
  }

#define EPILOG()                                                                      \
  {                                                                                   \
    _Pragma("unroll")                                                                 \
    for (int mi = 0; mi < 4; ++mi) {                                                  \
      const size_t row_ = bm + wm * 64 + mi * 16 + (lane & 15);                       \
      _Pragma("unroll")                                                               \
      for (int ni = 0; ni < 2; ++ni) {                                                \
        const size_t col_ = bn + wn * 32 + ni * 16 + ((lane >> 4) << 2);              \
        if (EPI == 0) {                                                               \
          ushort4 o_;                                                                 \
          o_.x = f2bf(acc[mi][ni][0] + biasv[ni][0]);                                 \
          o_.y = f2bf(acc[mi][ni][1] + biasv[ni][1]);                                 \
          o_.z = f2bf(acc[mi][ni][2] + biasv[ni][2]);                                 \
          o_.w = f2bf(acc[mi][ni][3] + biasv[ni][3]);                                 \
          *(ushort4*)((ushort*)Cout + row_ * CD + col_) = o_;                         \
        } else {                                                                      \
          f32x4 rs_ = *(const f32x4*)(resid + row_ * CD + col_);                      \
          f32x4 o_;                                                                   \
          o_[0] = acc[mi][ni][0] + biasv[ni][0] + rs_[0];                             \
          o_[1] = acc[mi][ni][1] + biasv[ni][1] + rs_[1];                             \
          o_[2] = acc[mi][ni][2] + biasv[ni][2] + rs_[2];                             \
          o_[3] = acc[mi][ni][3] + biasv[ni][3] + rs_[3];                             \
          *(f32x4*)((float*)Cout + row_ * CD + col_) = o_;                            \
        }                                                                             \
        acc[mi][ni] = (f32x4){0.f, 0.f, 0.f, 0.f};                                    \
      }                                                                               \
    }                                                                                 \
    asm volatile("" ::: "memory");                                                    \
  }

    // ---- tile 0
    KSTEP(0, 6, 1) KSTEP(1, 6, 1) KSTEP(2, 6, 1) KSTEP(3, 6, 1)
    KSTEP(4, 6, 1) KSTEP(5, 6, 1) KSTEP(6, 6, 1) KSTEP(7, 6, 1)
    EPILOG();
    bm += 128;

    // ---- middle tiles
    for (int tt = 1; tt < NT - 1; ++tt) {
        KSTEP(0, 6 + E, 1) KSTEP(1, 6 + E, 1) KSTEP(2, 6 + E, 1) KSTEP(3, 6 + E, 1)
        KSTEP(4, 6 + E, 1) KSTEP(5, 6 + E, 1) KSTEP(6, 6, 1)     KSTEP(7, 6, 1)
        EPILOG();
        bm += 128;
    }

    // ---- last tile
    KSTEP(0, 6 + E, 1) KSTEP(1, 6 + E, 1) KSTEP(2, 5 + E, 0) KSTEP(3, 4 + E, 0)
    KSTEP(4, 3 + E, 0) KSTEP(5, 2 + E, 0) KSTEP(6, 1, 0)     KSTEP(7, 0, 0)
    EPILOG();

#undef KSTEP
#undef EPILOG
}

// ---------------------------------------------------------------- edge attention
// v8: TWO queries per wave (grid QN/2, still 1-wave blocks -> independent
// retirement).  R8 evidence: time invariant in bytes (fp8 -40% bytes -> +15%
// time), VALU (4x range), occupancy (38-63%) => bound by per-wave fixed cost
// (WG dispatch + serialized src->gather round trips).  Interleaving two
// queries' chunk loops issues BOTH load sets before either compute: halves WG
// count and overlaps the latency chains.  Per-query math = proven v6 (bf16 kp).
__global__ __launch_bounds__(64) void edge_attn_k(const ushort* __restrict__ qp,
                                                  const ushort* __restrict__ kp,
                                                  const float* __restrict__ bias,
                                                  const int* __restrict__ src,
                                                  const int* __restrict__ row_lo,
                                                  ushort* __restrict__ ao,
                                                  float* __restrict__ simw) {
    const int lane = threadIdx.x;
    const int e    = lane >> 3;          // output-channel-block slot 0..7
    const int h    = lane & 7;           // head
    const int q0   = blockIdx.x << 1;
    const int q1   = q0 + 1;
    const int lo0  = row_lo[q0];
    const int mid  = row_lo[q0 + 1];
    const int hi1  = row_lo[q0 + 2];
    const int hi0  = mid, lo1 = mid;
    const int deg0 = hi0 - lo0, deg1 = hi1 - lo1;
    const float SC2 = SCL * LOG2E;

    // own q channels h*32+e*4 .. +3 (2 uints = 4 bf16), both queries
    const uint2 qvA = *(const uint2*)(qp + (size_t)q0 * CD + (h << 5) + (e << 2));
    const uint2 qvB = *(const uint2*)(qp + (size_t)q1 * CD + (h << 5) + (e << 2));

    f32x4 accA = {0.f, 0.f, 0.f, 0.f}, accB = {0.f, 0.f, 0.f, 0.f};
    float mA = -INFINITY, sA = 0.f, mB = -INFINITY, sB = 0.f;
    float wA0 = -INFINITY, wA1 = -INFINITY, wB0 = -INFINITY, wB1 = -INFINITY;

    // ---- load phase for one query's chunk (guards wave-uniform)
#define QLOAD(ON, BASE, HI, SV, BV, KU)                                               \
    int   SV = 0;                                                                     \
    float BV = 0.f;                                                                   \
    uint2 KU[8];                                                                      \
    _Pragma("unroll")                                                                 \
    for (int ep = 0; ep < 8; ++ep) { KU[ep].x = 0u; KU[ep].y = 0u; }                  \
    if (ON) {                                                                         \
        if (lane < 8 && (BASE) + lane < (HI)) SV = src[(BASE) + lane];                \
        if (lane < ((HI) - (BASE)) * 8) BV = bias[(size_t)(BASE) * NH + lane] * SC2;  \
        _Pragma("unroll")                                                             \
        for (int ep = 0; ep < 8; ++ep) {                                              \
            if ((BASE) + ep < (HI)) {                                                 \
                int sidx_ = __shfl(SV, ep);                                           \
                KU[ep] = *(const uint2*)(kp + (size_t)sidx_ * CD + (h << 5) + (e << 2)); \
            }                                                                         \
        }                                                                             \
    }

    // ---- compute phase for one query's chunk (v6 math, verbatim)
#define QCHUNK(QV, KU, BV, BASE, HI, LO, ACC, M, S, W0, W1, DEG)                      \
  {                                                                                   \
    float p_[8];                                                                      \
    _Pragma("unroll")                                                                 \
    for (int ep = 0; ep < 8; ++ep) {                                                  \
        float d_;                                                                     \
        d_ = blo(QV.x) * blo(KU[ep].x);                                               \
        d_ = fmaf(bhi(QV.x), bhi(KU[ep].x), d_);                                      \
        d_ = fmaf(blo(QV.y), blo(KU[ep].y), d_);                                      \
        d_ = fmaf(bhi(QV.y), bhi(KU[ep].y), d_);                                      \
        p_[ep] = d_;                                                                  \
    }                                                                                 \
    _Pragma("unroll")                                                                 \
    for (int r = 8; r <= 32; r <<= 1) {                                               \
        _Pragma("unroll")                                                             \
        for (int ep = 0; ep < 8; ++ep)                                                \
            p_[ep] += __shfl_xor(p_[ep], r);                                          \
    }                                                                                 \
    float sims_[8];                                                                   \
    _Pragma("unroll")                                                                 \
    for (int ep = 0; ep < 8; ++ep) {                                                  \
        float bvp_ = __shfl(BV, (ep << 3) + h);                                       \
        sims_[ep] = ((BASE) + ep < (HI)) ? fmaf(p_[ep], SC2, bvp_) : -INFINITY;       \
    }                                                                                 \
    float cmax_ = sims_[0];                                                           \
    _Pragma("unroll")                                                                 \
    for (int ep = 1; ep < 8; ++ep) cmax_ = fmaxf(cmax_, sims_[ep]);                   \
    const float mnew_  = fmaxf(M, cmax_);                                             \
    const float scale_ = fexp2(M - mnew_);                                            \
    ACC[0] *= scale_; ACC[1] *= scale_; ACC[2] *= scale_; ACC[3] *= scale_;           \
    float esum_ = 0.f;                                                                \
    _Pragma("unroll")                                                                 \
    for (int ep = 0; ep < 8; ++ep) {                                                  \
        const float ex_ = fexp2(sims_[ep] - mnew_);                                   \
        esum_ += ex_;                                                                 \
        ACC[0] = fmaf(ex_, blo(KU[ep].x), ACC[0]);                                    \
        ACC[1] = fmaf(ex_, bhi(KU[ep].x), ACC[1]);                                    \
        ACC[2] = fmaf(ex_, blo(KU[ep].y), ACC[2]);                                    \
        ACC[3] = fmaf(ex_, bhi(KU[ep].y), ACC[3]);                                    \
    }                                                                                 \
    S = S * scale_ + esum_;                                                           \
    M = mnew_;                                                                        \
    float ta_ = (e & 1) ? sims_[1] : sims_[0];                                        \
    float tb_ = (e & 1) ? sims_[3] : sims_[2];                                        \
    float tc_ = (e & 1) ? sims_[5] : sims_[4];                                        \
    float td_ = (e & 1) ? sims_[7] : sims_[6];                                        \
    float te_ = (e & 2) ? tb_ : ta_;                                                  \
    float tf_ = (e & 2) ? td_ : tc_;                                                  \
    float own_ = (e & 4) ? tf_ : te_;                                                 \
    if ((DEG) <= 16) {                                                                \
        if ((BASE) == (LO)) W0 = own_; else W1 = own_;                                \
    } else if ((BASE) + e < (HI)) {                                                   \
        simw[(size_t)(BASE) * NH + lane] = own_;                                      \
    }                                                                                 \
  }

    int baseA = lo0, baseB = lo1;
    const int nItA = (deg0 + 7) >> 3, nItB = (deg1 + 7) >> 3;
    const int nIt  = nItA > nItB ? nItA : nItB;
    for (int it = 0; it < nIt; ++it, baseA += 8, baseB += 8) {
        const bool onA = baseA < hi0;
        const bool onB = baseB < hi1;
        QLOAD(onA, baseA, hi0, svA, bvA, kuA)
        QLOAD(onB, baseB, hi1, svB, bvB, kuB)
        if (onA) QCHUNK(qvA, kuA, bvA, baseA, hi0, lo0, accA, mA, sA, wA0, wA1, deg0)
        if (onB) QCHUNK(qvB, kuB, bvB, baseB, hi1, lo1, accB, mB, sB, wB0, wB1, deg1)
    }
#undef QLOAD
#undef QCHUNK

    // ---- epilogue per query (v6 verbatim, x2)
    const float invA = 1.0f / (sA + 1e-8f);
    const float invB = 1.0f / (sB + 1e-8f);

    ushort4 oA, oB;
    oA.x = f2bf(accA[0] * invA); oA.y = f2bf(accA[1] * invA);
    oA.z = f2bf(accA[2] * invA); oA.w = f2bf(accA[3] * invA);
    *(ushort4*)(ao + (size_t)q0 * CD + (h << 5) + (e << 2)) = oA;
    oB.x = f2bf(accB[0] * invB); oB.y = f2bf(accB[1] * invB);
    oB.z = f2bf(accB[2] * invB); oB.w = f2bf(accB[3] * invB);
    *(ushort4*)(ao + (size_t)q1 * CD + (h << 5) + (e << 2)) = oB;

    if (deg0 > 0) {
        if (deg0 <= 8) {
            if (lane < (deg0 << 3))
                simw[(size_t)lo0 * NH + lane] = fexp2(wA0 - mA) * invA;
        } else if (deg0 <= 16) {
            simw[(size_t)lo0 * NH + lane] = fexp2(wA0 - mA) * invA;
            if (lane < ((deg0 - 8) << 3))
                simw[(size_t)(lo0 + 8) * NH + lane] = fexp2(wA1 - mA) * invA;
        } else {
            asm volatile("s_waitcnt vmcnt(0)" ::: "memory");   // drain sim stores
            for (int i = lane; i < deg0 * 8; i += 64) {
                size_t idx = (size_t)lo0 * NH + i;   // head = i&7 = lane&7 = h
                float v = simw[idx];
                simw[idx] = fexp2(v - mA) * invA;
            }
        }
    }
    if (deg1 > 0) {
        if (deg1 <= 8) {
            if (lane < (deg1 << 3))
                simw[(size_t)lo1 * NH + lane] = fexp2(wB0 - mB) * invB;
        } else if (deg1 <= 16) {
            simw[(size_t)lo1 * NH + lane] = fexp2(wB0 - mB) * invB;
            if (lane < ((deg1 - 8) << 3))
                simw[(size_t)(lo1 + 8) * NH + lane] = fexp2(wB1 - mB) * invB;
        } else {
            asm volatile("s_waitcnt vmcnt(0)" ::: "memory");   // drain sim stores
            for (int i = lane; i < deg1 * 8; i += 64) {
                size_t idx = (size_t)lo1 * NH + i;
                float v = simw[idx];
                simw[idx] = fexp2(v - mB) * invB;
            }
        }
    }
}

// ---------------------------------------------------------------- launch
extern "C" void kernel_launch(void* const* d_in, const int* in_sizes, int n_in,
                              void* d_out, int out_size, void* d_ws, size_t ws_size,
                              hipStream_t stream) {
    const float* q    = (const float*)d_in[0];
    const float* k    = (const float*)d_in[1];
    const float* bias = (const float*)d_in[2];
    const float* lnw  = (const float*)d_in[3];
    const float* lnb  = (const float*)d_in[4];
    const float* wq   = (const float*)d_in[5];
    const float* bq   = (const float*)d_in[6];
    const float* wk   = (const float*)d_in[7];
    const float* bk   = (const float*)d_in[8];
    const float* wo   = (const float*)d_in[9];
    const float* bo   = (const float*)d_in[10];
    const int*   src  = (const int*)d_in[11];
    const int*   dst  = (const int*)d_in[12];

    float* out_m = (float*)d_out;                   // [QN][CD] fp32
    float* out_w = out_m + (size_t)QN * CD;         // [NE][NH] fp32 (weights)

    ushort* qn_b = (ushort*)d_ws;                   // [QN][CD]  LN(q) bf16 -> reused as attn_out
    ushort* qp_b = qn_b + (size_t)QN * CD;          // [QN][CD]  qp bf16
    ushort* kp_b = qp_b + (size_t)QN * CD;          // [KVN][CD] kp bf16
    ushort* wb   = kp_b + (size_t)KVN * CD;         // 3 x [256*256] bf16 weights
    int*    rowlo = (int*)(wb + 3 * 65536);         // [QN+1]

    // kb (k converted to bf16) lives in the out_m region: consumed by gemm2<0>,
    // and out_m is only written by the final gemm2<1>.
    ushort* kb = (ushort*)d_out;                    // [KVN][CD] bf16 (32 MB of 64)

    prep_k<<<dim3(LNB + 192 + RLB + LNB), dim3(256), 0, stream>>>(
        q, k, lnw, lnb, wq, wk, wo, dst, qn_b, kb, wb, rowlo);

    // z=0: qp = LN(q)@wq ; z=1: kp = kb@wk   (both bf16, identical blocks)
    gemm2_k<0, 8><<<dim3(64, 2, 2), dim3(512), 0, stream>>>(
        qn_b, kb, wb, wb + 65536, bq, bk, nullptr, qp_b, kp_b);

    edge_attn_k<<<dim3(QN / 2), dim3(64), 0, stream>>>(
        qp_b, kp_b, bias, src, rowlo, qn_b /*ao*/, out_w);

    // out = attn_out@wo + bo + q
    gemm2_k<1, 4><<<dim3(128, 2, 1), dim3(512), 0, stream>>>(
        qn_b, qn_b, wb + 131072, wb + 131072, bo, bo, q, out_m, out_m);
}

// Round 10
// 170.566 us; speedup vs baseline: 1.0856x; 1.0679x over previous
//
#include <hip/hip_runtime.h>
#include <cmath>

#define QN    65536
#define KVN   65536
#define CD    256
#define NH    8
#define NE    524288
#define SCL   0.0625f      // 1/sqrt(256)
#define LNEPS 1e-5f
#define LOG2E 1.4426950408889634f

typedef __bf16 bf16x8 __attribute__((ext_vector_type(8)));
typedef float  f32x4  __attribute__((ext_vector_type(4)));

__device__ __forceinline__ float b2f(ushort u) {
    return __builtin_bit_cast(float, (unsigned)u << 16);
}
__device__ __forceinline__ ushort f2bf(float f) {
    unsigned u = __builtin_bit_cast(unsigned, f);
    return (ushort)((u + 0x7FFFu + ((u >> 16) & 1u)) >> 16);   // RNE
}

#if __has_builtin(__builtin_amdgcn_exp2f)
__device__ __forceinline__ float fexp2(float x) { return __builtin_amdgcn_exp2f(x); }
#else
__device__ __forceinline__ float fexp2(float x) {
    float r; asm volatile("v_exp_f32 %0, %1" : "=v"(r) : "v"(x)); return r;
}
#endif

#define GLD16(g, l) __builtin_amdgcn_global_load_lds( \
    (const __attribute__((address_space(1))) unsigned int*)(const void*)(g), \
    (__attribute__((address_space(3))) unsigned int*)(void*)(l), 16, 0, 0)

// ---------------------------------------------------------------- fused prep:
// blk [0, LNB):          LN(q) -> bf16 qn           (4 rows/block)
// blk [LNB, LNB+192):    wq|wk|wo fp32 -> bf16      (1024 els/block)
// blk [.., +NE/256):     CSR row_lo fill
// blk [.., +LNB):        k fp32 -> bf16 kb          (4 rows/block)
#define LNB   (QN / 4)
#define RLB   (NE / 256)
__global__ __launch_bounds__(256) void prep_k(const float* __restrict__ q,
                                              const float* __restrict__ k,
                                              const float* __restrict__ lnw,
                                              const float* __restrict__ lnb,
                                              const float* __restrict__ wq,
                                              const float* __restrict__ wk,
                                              const float* __restrict__ wo,
                                              const int* __restrict__ dst,
                                              ushort* __restrict__ qn,
                                              ushort* __restrict__ kb,
                                              ushort* __restrict__ wb,
                                              int* __restrict__ row_lo) {
    const int blk = blockIdx.x;
    if (blk < LNB) {
        int row  = (blk << 2) + (threadIdx.x >> 6);
        int lane = threadIdx.x & 63;
        float4 v = *(const float4*)(q + (size_t)row * CD + (lane << 2));
        float s  = v.x + v.y + v.z + v.w;
        float s2 = v.x * v.x + v.y * v.y + v.z * v.z + v.w * v.w;
        #pragma unroll
        for (int m = 1; m < 64; m <<= 1) {
            s  += __shfl_xor(s, m);
            s2 += __shfl_xor(s2, m);
        }
        float mu   = s * (1.0f / CD);
        float rstd = rsqrtf(s2 * (1.0f / CD) - mu * mu + LNEPS);
        float4 w = *(const float4*)(lnw + (lane << 2));
        float4 b = *(const float4*)(lnb + (lane << 2));
        ushort4 o;
        o.x = f2bf((v.x - mu) * rstd * w.x + b.x);
        o.y = f2bf((v.y - mu) * rstd * w.y + b.y);
        o.z = f2bf((v.z - mu) * rstd * w.z + b.z);
        o.w = f2bf((v.w - mu) * rstd * w.w + b.w);
        *(ushort4*)(qn + (size_t)row * CD + (lane << 2)) = o;
    } else if (blk < LNB + 192) {
        int idx4 = ((blk - LNB) * 256 + threadIdx.x) * 4;   // 0 .. 3*65536
        int mat  = idx4 >> 16;
        int off  = idx4 & 65535;
        const float* src = (mat == 0) ? wq : (mat == 1) ? wk : wo;
        float4 v = *(const float4*)(src + off);
        ushort4 o;
        o.x = f2bf(v.x); o.y = f2bf(v.y); o.z = f2bf(v.z); o.w = f2bf(v.w);
        *(ushort4*)(wb + idx4) = o;
    } else if (blk < LNB + 192 + RLB) {
        int e = (blk - LNB - 192) * 256 + threadIdx.x;
        int d     = dst[e];
        int dprev = (e == 0) ? -1 : dst[e - 1];
        for (int qq = dprev + 1; qq <= d; ++qq) row_lo[qq] = e;
        if (e == NE - 1)
            for (int qq = d + 1; qq <= QN; ++qq) row_lo[qq] = NE;
    } else {
        int row  = ((blk - LNB - 192 - RLB) << 2) + (threadIdx.x >> 6);
        int lane = threadIdx.x & 63;
        float4 v = *(const float4*)(k + (size_t)row * CD + (lane << 2));
        ushort4 o;
        o.x = f2bf(v.x); o.y = f2bf(v.y); o.z = f2bf(v.z); o.w = f2bf(v.w);
        *(ushort4*)(kb + (size_t)row * CD + (lane << 2)) = o;
    }
}

// ---------------------------------------------------------------- persistent bf16 GEMM
// Proven R2 kernel, byte-identical. One block per CU (LDS 128 KB), 512 threads
// = 8 waves (2m x 4n), tile 128x128. B panel in LDS once; A via 8-slot GLD16
// ring, stage-ahead-6, counted vmcnt; one barrier per K-step; swapped-operand
// MFMA -> vectorized epilogue. EPI 0: bf16 out (E=8). EPI 1: f32 + resid (E=16).
template<int EPI, int NT>
__global__ __launch_bounds__(512) void gemm2_k(const ushort* __restrict__ A0,
                                               const ushort* __restrict__ A1,
                                               const ushort* __restrict__ B0,
                                               const ushort* __restrict__ B1,
                                               const float* __restrict__ bias0,
                                               const float* __restrict__ bias1,
                                               const float* __restrict__ resid,
                                               void* __restrict__ C0,
                                               void* __restrict__ C1) {
    const bool second = (blockIdx.z != 0);
    const ushort* Ap   = second ? A1 : A0;
    const ushort* B    = second ? B1 : B0;
    const float*  bias = second ? bias1 : bias0;
    void*         Cout = second ? C1 : C0;

    __shared__ __align__(16) ushort Bs[8][4096];   // 64 KB: full B panel, 8 k-slices
    __shared__ __align__(16) ushort As[8][4096];   // 64 KB: A ring, 8 slots

    const int t    = threadIdx.x;
    const int lane = t & 63;
    const int wid  = t >> 6;             // 0..7
    const int wm   = wid & 1;            // 2 wave-rows
    const int wn   = wid >> 1;           // 4 wave-cols
    const size_t bn  = (size_t)blockIdx.y * 128;
    size_t bm = (size_t)blockIdx.x * (NT * 128);

    const int sr = t >> 2;               // 0..127 staging row
    const int sc = (t & 3) * 8;          // staging col (8 elems = 16B)

    constexpr int E = (EPI == 0) ? 8 : 16;   // epilogue vmem instrs

    f32x4 acc[4][2] = {};
    f32x4 biasv[2];
    #pragma unroll
    for (int ni = 0; ni < 2; ++ni)
        biasv[ni] = *(const f32x4*)(bias + bn + wn * 32 + ni * 16 + ((lane >> 4) << 2));

    // ---- prologue: whole B panel + A slots 0..5
    #pragma unroll
    for (int s = 0; s < 8; ++s)
        GLD16(B + (bn + sr) * CD + (s << 5) + sc, &Bs[s][wid << 9]);
    #pragma unroll
    for (int s = 0; s < 6; ++s)
        GLD16(Ap + (bm + sr) * CD + (s << 5) + sc, &As[s][wid << 9]);
    asm volatile("" : "+v"(biasv[0]), "+v"(biasv[1]));

#define KSTEP(KT, VM, GUARD)                                                          \
  {                                                                                   \
    if (GUARD) {                                                                      \
      const ushort* ga_ = Ap + (bm + (((KT) >= 2) ? 128 : 0) + sr) * CD               \
                          + ((((KT) + 6) & 7) << 5) + sc;                             \
      GLD16(ga_, &As[((KT) + 6) & 7][wid << 9]);                                      \
    }                                                                                 \
    asm volatile("s_waitcnt vmcnt(%0) lgkmcnt(0)\n\ts_barrier" :: "i"(VM) : "memory");\
    {                                                                                 \
      const int kq_ = (lane >> 4) << 3;                                               \
      bf16x8 af_[4], bg_[2];                                                          \
      _Pragma("unroll")                                                               \
      for (int mi = 0; mi < 4; ++mi)                                                  \
        af_[mi] = *(const bf16x8*)&As[(KT) & 7][((wm * 64 + mi * 16 + (lane & 15)) << 5) + kq_]; \
      _Pragma("unroll")                                                               \
      for (int ni = 0; ni < 2; ++ni)                                                  \
        bg_[ni] = *(const bf16x8*)&Bs[(KT)][((wn * 32 + ni * 16 + (lane & 15)) << 5) + kq_];     \
      _Pragma("unroll")                                                               \
      for (int mi = 0; mi < 4; ++mi)                                                  \
        _Pragma("unroll")                                                             \
        for (int ni = 0; ni < 2; ++ni)                                                \
          acc[mi][ni] = __builtin_amdgcn_mfma_f32_16x16x32_bf16(bg_[ni], af_[mi], acc[mi][ni], 0, 0, 0); \
    }                                                                                 \
  }

#define EPILOG()                                                                      \
  {                                                                                   \
    _Pragma("unroll")                                                                 \
    for (int mi = 0; mi < 4; ++mi) {                                                  \
      const size_t row_ = bm + wm * 64 + mi * 16 + (lane & 15);                       \
      _Pragma("unroll")                                                               \
      for (int ni = 0; ni < 2; ++ni) {                                                \
        const size_t col_ = bn + wn * 32 + ni * 16 + ((lane >> 4) << 2);              \
        if (EPI == 0) {                                                               \
          ushort4 o_;                                                                 \
          o_.x = f2bf(acc[mi][ni][0] + biasv[ni][0]);                                 \
          o_.y = f2bf(acc[mi][ni][1] + biasv[ni][1]);                                 \
          o_.z = f2bf(acc[mi][ni][2] + biasv[ni][2]);                                 \
          o_.w = f2bf(acc[mi][ni][3] + biasv[ni][3]);                                 \
          *(ushort4*)((ushort*)Cout + row_ * CD + col_) = o_;                         \
        } else {                                                                      \
          f32x4 rs_ = *(const f32x4*)(resid + row_ * CD + col_);                      \
          f32x4 o_;                                                                   \
          o_[0] = acc[mi][ni][0] + biasv[ni][0] + rs_[0];                             \
          o_[1] = acc[mi][ni][1] + biasv[ni][1] + rs_[1];                             \
          o_[2] = acc[mi][ni][2] + biasv[ni][2] + rs_[2];                             \
          o_[3] = acc[mi][ni][3] + biasv[ni][3] + rs_[3];                             \
          *(f32x4*)((float*)Cout + row_ * CD + col_) = o_;                            \
        }                                                                             \
        acc[mi][ni] = (f32x4){0.f, 0.f, 0.f, 0.f};                                    \
      }                                                                               \
    }                                                                                 \
    asm volatile("" ::: "memory");                                                    \
  }

    // ---- tile 0
    KSTEP(0, 6, 1) KSTEP(1, 6, 1) KSTEP(2, 6, 1) KSTEP(3, 6, 1)
    KSTEP(4, 6, 1) KSTEP(5, 6, 1) KSTEP(6, 6, 1) KSTEP(7, 6, 1)
    EPILOG();
    bm += 128;

    // ---- middle tiles
    for (int tt = 1; tt < NT - 1; ++tt) {
        KSTEP(0, 6 + E, 1) KSTEP(1, 6 + E, 1) KSTEP(2, 6 + E, 1) KSTEP(3, 6 + E, 1)
        KSTEP(4, 6 + E, 1) KSTEP(5, 6 + E, 1) KSTEP(6, 6, 1)     KSTEP(7, 6, 1)
        EPILOG();
        bm += 128;
    }

    // ---- last tile
    KSTEP(0, 6 + E, 1) KSTEP(1, 6 + E, 1) KSTEP(2, 5 + E, 0) KSTEP(3, 4 + E, 0)
    KSTEP(4, 3 + E, 0) KSTEP(5, 2 + E, 0) KSTEP(6, 1, 0)     KSTEP(7, 0, 0)
    EPILOG();

#undef KSTEP
#undef EPILOG
}

// ---------------------------------------------------------------- edge attention
// CHAMPION kernel (R2, 69.7us) restored byte-for-byte, plus a bijective
// XCD-contiguous query mapping (the only change; pure block permutation).
// Evidence across R5-R9: time invariant under -75% VALU, -40% bytes, -50% WGs,
// 2x MLP; the smallest-VGPR serial kernel (36 VGPR -> max resident waves) wins.
// The gather stream (524K random 512-B kp rows, ~8x reuse that per-XCD L2s
// cannot share) sets the ~70us request-latency floor.
__global__ __launch_bounds__(64) void edge_attn_k(const ushort* __restrict__ qp,
                                                  const ushort* __restrict__ kp,
                                                  const float* __restrict__ bias,
                                                  const int* __restrict__ src,
                                                  const int* __restrict__ row_lo,
                                                  ushort* __restrict__ ao,
                                                  float* __restrict__ simw) {
    const int bid  = blockIdx.x;
    const int q    = ((bid & 7) << 13) + (bid >> 3);   // XCD-contiguous ranges
    const int lane = threadIdx.x;
    const int lo = row_lo[q];
    const int hi = row_lo[q + 1];
    const int deg = hi - lo;
    const float SC2 = SCL * LOG2E;

    ushort4 qu = *(const ushort4*)(qp + (size_t)q * CD + (lane << 2));
    float4 qv = {b2f(qu.x) * SC2, b2f(qu.y) * SC2, b2f(qu.z) * SC2, b2f(qu.w) * SC2};
    float4 acc = {0.f, 0.f, 0.f, 0.f};
    float m = -INFINITY, s = 0.f;
    float wval0 = 0.f, wval1 = 0.f;      // chunk-0 / chunk-1 transposed sims

    for (int base = lo; base < hi; base += 8) {
        const int cnum = (base - lo) >> 3;
        // ---- load phase: 1 src chunk + 1 bias chunk + up to 8 kp rows
        int sv = 0;
        if (lane < 8 && base + lane < hi) sv = src[base + lane];
        float bch = 0.f;
        if (lane < (hi - base) * 8) bch = bias[(size_t)base * NH + lane] * SC2;
        ushort4 ku[8];
        #pragma unroll
        for (int i = 0; i < 8; ++i) {
            if (base + i < hi) {
                int sidx = __shfl(sv, i);
                ku[i] = *(const ushort4*)(kp + (size_t)sidx * CD + (lane << 2));
            }
        }
        // ---- per-edge compute (online softmax, log2 domain)
        #pragma unroll
        for (int i = 0; i < 8; ++i) {
            if (base + i < hi) {
                float4 kv = {b2f(ku[i].x), b2f(ku[i].y), b2f(ku[i].z), b2f(ku[i].w)};
                float d = qv.x * kv.x + qv.y * kv.y + qv.z * kv.z + qv.w * kv.w;
                d += __shfl_xor(d, 1);
                d += __shfl_xor(d, 2);
                d += __shfl_xor(d, 4);
                float bvi = __shfl(bch, (i << 3) + (lane >> 3));
                float sim = d + bvi;                       // log2 domain
                float tw = __shfl(sim, (lane & 7) << 3);   // capture for weights output
                bool mine = ((lane >> 3) == i);
                if (deg <= 16) {
                    if (cnum == 0) wval0 = mine ? tw : wval0;
                    else           wval1 = mine ? tw : wval1;
                } else {
                    wval0 = mine ? tw : wval0;             // rolling (staged per chunk)
                }
                float mnew  = fmaxf(m, sim);
                float scale = fexp2(m - mnew);             // first edge: exp2(-inf)=0
                float ex    = fexp2(sim - mnew);
                s = s * scale + ex;
                acc.x = acc.x * scale + ex * kv.x;
                acc.y = acc.y * scale + ex * kv.y;
                acc.z = acc.z * scale + ex * kv.z;
                acc.w = acc.w * scale + ex * kv.w;
                m = mnew;
            }
        }
        // ---- stage raw (log2) sims only for deg>16 queries (rare)
        if (deg > 16) {
            int lim = hi - base; if (lim > 8) lim = 8;
            if (lane < lim * 8) simw[(size_t)base * NH + lane] = wval0;
        }
    }

    float ws  = s + 1e-8f;
    float inv = 1.0f / ws;
    ushort4 o;
    o.x = f2bf(acc.x * inv);
    o.y = f2bf(acc.y * inv);
    o.z = f2bf(acc.z * inv);
    o.w = f2bf(acc.w * inv);
    *(ushort4*)(ao + (size_t)q * CD + (lane << 2)) = o;

    if (deg > 0) {
        const float mm = __shfl(m,   (lane & 7) << 3);     // state of head lane&7
        const float ii = __shfl(inv, (lane & 7) << 3);
        if (deg <= 8) {
            if (lane < deg * 8)
                simw[(size_t)lo * NH + lane] = fexp2(wval0 - mm) * ii;
        } else if (deg <= 16) {
            simw[(size_t)lo * NH + lane] = fexp2(wval0 - mm) * ii;          // edges lo..lo+7
            if (lane < (deg - 8) * 8)
                simw[(size_t)(lo + 8) * NH + lane] = fexp2(wval1 - mm) * ii; // edges lo+8..
        } else {
            asm volatile("s_waitcnt vmcnt(0)" ::: "memory");   // drain sim stores
            for (int i = lane; i < deg * 8; i += 64) {
                size_t idx = (size_t)lo * NH + i;          // head = i&7 = lane&7
                float v = simw[idx];
                simw[idx] = fexp2(v - mm) * ii;
            }
        }
    }
}

// ---------------------------------------------------------------- launch
extern "C" void kernel_launch(void* const* d_in, const int* in_sizes, int n_in,
                              void* d_out, int out_size, void* d_ws, size_t ws_size,
                              hipStream_t stream) {
    const float* q    = (const float*)d_in[0];
    const float* k    = (const float*)d_in[1];
    const float* bias = (const float*)d_in[2];
    const float* lnw  = (const float*)d_in[3];
    const float* lnb  = (const float*)d_in[4];
    const float* wq   = (const float*)d_in[5];
    const float* bq   = (const float*)d_in[6];
    const float* wk   = (const float*)d_in[7];
    const float* bk   = (const float*)d_in[8];
    const float* wo   = (const float*)d_in[9];
    const float* bo   = (const float*)d_in[10];
    const int*   src  = (const int*)d_in[11];
    const int*   dst  = (const int*)d_in[12];

    float* out_m = (float*)d_out;                   // [QN][CD] fp32
    float* out_w = out_m + (size_t)QN * CD;         // [NE][NH] fp32 (weights)

    ushort* qn_b = (ushort*)d_ws;                   // [QN][CD]  LN(q) bf16 -> reused as attn_out
    ushort* qp_b = qn_b + (size_t)QN * CD;          // [QN][CD]  qp bf16
    ushort* kp_b = qp_b + (size_t)QN * CD;          // [KVN][CD] kp bf16
    ushort* wb   = kp_b + (size_t)KVN * CD;         // 3 x [256*256] bf16 weights
    int*    rowlo = (int*)(wb + 3 * 65536);         // [QN+1]

    // kb (k converted to bf16) lives in the out_m region: consumed by gemm2<0>,
    // and out_m is only written by the final gemm2<1>.
    ushort* kb = (ushort*)d_out;                    // [KVN][CD] bf16 (32 MB of 64)

    prep_k<<<dim3(LNB + 192 + RLB + LNB), dim3(256), 0, stream>>>(
        q, k, lnw, lnb, wq, wk, wo, dst, qn_b, kb, wb, rowlo);

    // z=0: qp = LN(q)@wq ; z=1: kp = kb@wk   (both bf16, identical blocks)
    gemm2_k<0, 8><<<dim3(64, 2, 2), dim3(512), 0, stream>>>(
        qn_b, kb, wb, wb + 65536, bq, bk, nullptr, qp_b, kp_b);

    edge_attn_k<<<dim3(QN), dim3(64), 0, stream>>>(
        qp_b, kp_b, bias, src, rowlo, qn_b /*ao*/, out_w);

    // out = attn_out@wo + bo + q
    gemm2_k<1, 4><<<dim3(128, 2, 1), dim3(512), 0, stream>>>(
        qn_b, qn_b, wb + 131072, wb + 131072, bo, bo, q, out_m, out_m);
}